// Round 4
// baseline (221.852 us; speedup 1.0000x reference)
//
#include <hip/hip_runtime.h>
#include <math.h>

#define TLEN 4096
#define BD   1024
#define HDIM 64
#define NB   4

typedef __attribute__((ext_vector_type(8))) short bf16x8;
typedef __attribute__((ext_vector_type(4))) float f32x4;
typedef __attribute__((ext_vector_type(16))) float f32x16;

__device__ __forceinline__ unsigned short f2bf(float f) {
    union { float f; unsigned u; } v; v.f = f;
    unsigned r = v.u + 0x7FFF + ((v.u >> 16) & 1);   // RNE
    return (unsigned short)(r >> 16);
}

// packed f32x2 -> bf16x2 (RNE), lo = first arg. Harness-validated in R10.
__device__ __forceinline__ unsigned cvt_pk_bf16(float lo, float hi) {
    unsigned r;
    asm("v_cvt_pk_bf16_f32 %0, %1, %2" : "=v"(r) : "v"(lo), "v"(hi));
    return r;
}

// 8x fp32 -> bf16x8 via 4 packed converts
__device__ __forceinline__ bf16x8 cvt8pk(const float4 a, const float4 b) {
    union { unsigned u[4]; bf16x8 v; } r;
    r.u[0] = cvt_pk_bf16(a.x, a.y);
    r.u[1] = cvt_pk_bf16(a.z, a.w);
    r.u[2] = cvt_pk_bf16(b.x, b.y);
    r.u[3] = cvt_pk_bf16(b.z, b.w);
    return r.v;
}

// ---------------------------------------------------------------------------
// Kernel 0: weights fp32 -> bf16, wbf[192][1024]
// ---------------------------------------------------------------------------
__global__ __launch_bounds__(256) void wconv_kernel(
    const float* __restrict__ wq, const float* __restrict__ wk,
    const float* __restrict__ wv, unsigned short* __restrict__ wbf)
{
    const int r = blockIdx.x;
    const float* src = (r < 64) ? wq : (r < 128) ? wk : wv;
    const int rr = r & 63;
    const int c  = threadIdx.x * 4;
    float4 a = *(const float4*)&src[(size_t)rr * BD + c];
    uint2 o;
    o.x = cvt_pk_bf16(a.x, a.y);
    o.y = cvt_pk_bf16(a.z, a.w);
    *(uint2*)&wbf[(size_t)r * BD + c] = o;
}

// ---------------------------------------------------------------------------
// Kernel 1: QKV projection. 512 blocks x 4 waves, 32 rows/block, BK=64.
// R13: 2-DEEP register prefetch. R12 diagnosis: at 1-deep, the ds_write at
// iter end waits vmcnt on loads issued ~400 cyc earlier, but x is HBM
// (~900 cyc) and W first-touch is cross-XCD — every iter stalled ~500 cyc
// with only 2 waves/SIMD to cover (MfmaUtil/VALUBusy ~5%). Now: loads for
// it+2 issue at iter start (W BEFORE x, so in-order vmcnt drain for W never
// waits on fresh HBM x); writes for it+1 (regs loaded LAST iter, ~1700 cyc
// coverage) go after compute. Reg parity p == target-iter&1 == LDS buf idx.
// ---------------------------------------------------------------------------
__global__ __launch_bounds__(256, 2) void qkv_kernel(
    const float* __restrict__ x,
    const unsigned short* __restrict__ wbf,
    unsigned short* __restrict__ Qb,
    unsigned short* __restrict__ Kb,
    unsigned short* __restrict__ Vt)
{
    const int r0   = blockIdx.x * 32;
    const int tid  = threadIdx.x;
    const int lane = tid & 63;
    const int w    = tid >> 6;
    const int g    = lane >> 4;
    const int c    = lane & 15;

    __shared__ __align__(16) unsigned short wsh[2][192 * 64];  // 24 KB each
    __shared__ __align__(16) float          xf[2][32 * 64];    // 8 KB each (fp32)
    __shared__ __align__(16) unsigned short vtr[64][40];       // V transpose

    f32x4 acc[3][2];
    #pragma unroll
    for (int t = 0; t < 3; ++t)
        #pragma unroll
        for (int rg = 0; rg < 2; ++rg) acc[t][rg] = (f32x4){0.f, 0.f, 0.f, 0.f};

    uint4 wrg[2][6], xrg[2][2];   // 2-deep staging regs (parity = target it&1)

    // W: coalesced loads (L2 after warm). lds chunk L&7 holds global (L&7)^(row&7).
    #define LOAD_W2(P, k0s)                                                     \
        {                                                                       \
            _Pragma("unroll")                                                   \
            for (int ii = 0; ii < 6; ++ii) {                                    \
                const int L   = ii * 256 + tid;                                 \
                const int row = L >> 3;                                         \
                const int jl  = (L & 7) ^ (row & 7);                            \
                wrg[P][ii] = *(const uint4*)&wbf[(size_t)row * BD + (k0s) + jl * 8]; \
            }                                                                   \
        }
    #define WRITE_W2(P)                                                         \
        {                                                                       \
            _Pragma("unroll")                                                   \
            for (int ii = 0; ii < 6; ++ii) {                                    \
                const int L = ii * 256 + tid;                                   \
                *(uint4*)&wsh[P][L * 8] = wrg[P][ii];                           \
            }                                                                   \
        }
    // x: coalesced fp32 HBM loads; lds chunk ch holds global chunk ch^(row&15).
    #define LOAD_X2(P, k0s)                                                     \
        {                                                                       \
            _Pragma("unroll")                                                   \
            for (int ii = 0; ii < 2; ++ii) {                                    \
                const int L   = ii * 256 + tid;                                 \
                const int row = L >> 4;                                         \
                const int gch = (L & 15) ^ (row & 15);                          \
                xrg[P][ii] = *(const uint4*)&x[(size_t)(r0 + row) * BD + (k0s) + gch * 4]; \
            }                                                                   \
        }
    #define WRITE_X2(P)                                                         \
        {                                                                       \
            _Pragma("unroll")                                                   \
            for (int ii = 0; ii < 2; ++ii) {                                    \
                const int L = ii * 256 + tid;                                   \
                *(uint4*)&xf[P][L * 4] = xrg[P][ii];                            \
            }                                                                   \
        }

    #define QKV_BODY(itv, cbv, PW)                                              \
        {                                                                       \
            __syncthreads();   /* buf[cbv] staged */                            \
            if ((itv) < 14) {                                                   \
                LOAD_W2(cbv, ((itv) + 2) * 64)   /* W first (in-order vmcnt) */ \
                LOAD_X2(cbv, ((itv) + 2) * 64)                                  \
            }                                                                   \
            _Pragma("unroll")                                                   \
            for (int h = 0; h < 2; ++h) {                                       \
                const int oct = h * 4 + g;                                      \
                bf16x8 aX[2], bW[3];                                            \
                _Pragma("unroll")                                               \
                for (int rg = 0; rg < 2; ++rg) {                                \
                    const int row = rg * 16 + c;                                \
                    const float4 a0 = *(const float4*)                          \
                        &xf[cbv][row * 64 + ((2 * oct) ^ c) * 4];               \
                    const float4 a1 = *(const float4*)                          \
                        &xf[cbv][row * 64 + ((2 * oct + 1) ^ c) * 4];           \
                    aX[rg] = cvt8pk(a0, a1);                                    \
                }                                                               \
                _Pragma("unroll")                                               \
                for (int t = 0; t < 3; ++t)                                     \
                    bW[t] = *(const bf16x8*)                                    \
                        &wsh[cbv][((w * 3 + t) * 16 + c) * 64                   \
                                  + ((oct ^ (c & 7)) * 8)];                     \
                _Pragma("unroll")                                               \
                for (int t = 0; t < 3; ++t)                                     \
                    _Pragma("unroll")                                           \
                    for (int rg = 0; rg < 2; ++rg)                              \
                        acc[t][rg] = __builtin_amdgcn_mfma_f32_16x16x32_bf16(   \
                            aX[rg], bW[t], acc[t][rg], 0, 0, 0);                \
            }                                                                   \
            if ((itv) < 15) {                                                   \
                WRITE_W2(PW)   /* it+1 data; regs loaded LAST iter */           \
                WRITE_X2(PW)                                                    \
            }                                                                   \
        }

    // prologue: stage iter 0 (pays one full vmcnt drain), prefetch iter 1 regs
    LOAD_W2(0, 0)
    LOAD_X2(0, 0)
    WRITE_W2(0)
    WRITE_X2(0)
    LOAD_W2(1, 64)
    LOAD_X2(1, 64)

    #pragma unroll
    for (int it2 = 0; it2 < 8; ++it2) {
        QKV_BODY(2 * it2,     0, 1)
        QKV_BODY(2 * it2 + 1, 1, 0)
    }

    // ---- epilogue.  C/D frag: row = rg*16 + g*4 + i, col = c (tile m)
    const float qscale = 0.18033688f;   // 0.125 * log2(e)
    const int   bb     = r0 / TLEN;
    const int   trow   = r0 % TLEN;
    #pragma unroll
    for (int t = 0; t < 3; ++t) {
        const int m = w * 3 + t;
        #pragma unroll
        for (int rg = 0; rg < 2; ++rg)
            #pragma unroll
            for (int i = 0; i < 4; ++i) {
                const int row = rg * 16 + g * 4 + i;
                if (m < 4)
                    Qb[(size_t)(r0 + row) * HDIM + m * 16 + c]
                        = f2bf(acc[t][rg][i] * qscale);
                else if (m < 8)
                    Kb[(size_t)(r0 + row) * HDIM + (m - 4) * 16 + c]
                        = f2bf(acc[t][rg][i]);
                else
                    vtr[(m - 8) * 16 + c][row] = f2bf(acc[t][rg][i]);
            }
    }
    __syncthreads();
    {
        const int d    = tid >> 2;
        const int part = tid & 3;
        uint4 v0 = *(const uint4*)&vtr[d][part * 8];
        unsigned short* dst = Vt + (size_t)bb * HDIM * TLEN + (size_t)d * TLEN
                            + trow + part * 8;
        *(uint4*)&dst[0] = v0;
    }
    #undef LOAD_W2
    #undef WRITE_W2
    #undef LOAD_X2
    #undef WRITE_X2
    #undef QKV_BODY
}

// ---------------------------------------------------------------------------
// Kernel 2: flash attention. 256-thr blocks, 4 waves x 32 q-rows = 128q-block.
// R10: 32x32x16 MFMA path, P fully in-register (cvt_pk + permlane32_swap).
// R11: setprio(1) around MFMA clusters. R13: WRITE_KV moved AFTER PV —
// vmcnt coverage for the K/V loads grows from the short S-phase (~250 cyc,
// < first-touch latency) to the full iteration (~1200 cyc), and PV's lgkm
// waits no longer count the 4 staging ds_writes.
// ---------------------------------------------------------------------------
template <int KEYS>
__global__ __launch_bounds__(256, 2) void attn_kernel(
    const unsigned short* __restrict__ Qb,
    const unsigned short* __restrict__ Kb,
    const unsigned short* __restrict__ Vt,
    float* __restrict__ O1, float* __restrict__ Ml, float* __restrict__ out)
{
    const int b     = blockIdx.y;
    const int q0    = blockIdx.x * 128;
    const int split = blockIdx.z;
    const int sbase = split * KEYS;

    const unsigned short* Qp = Qb + (size_t)b * TLEN * HDIM;
    const unsigned short* Kp = Kb + (size_t)b * TLEN * HDIM + (size_t)sbase * HDIM;
    const unsigned short* Vp = Vt + (size_t)b * HDIM * TLEN + sbase;

    const int tid  = threadIdx.x;
    const int lane = tid & 63;
    const int w    = tid >> 6;
    const int ql   = lane & 31;   // q row of S^T/O (A row, D col); d col in vB
    const int hi   = lane >> 5;
    const int ch   = lane & 7;    // XOR swizzle component

    __shared__ __align__(16) unsigned short ksh[2][4096];   // swizzled [key][d]
    __shared__ __align__(16) unsigned short vsh[2][4096];   // swizzled [d][key]

    // Q B-frags: B[k=16][col=q], col=lane&31, k=hi*8+j. qB[s] covers d=16s..16s+15
    bf16x8 qB[4];
    #pragma unroll
    for (int s = 0; s < 4; ++s)
        qB[s] = *(const bf16x8*)
            &Qp[(size_t)(q0 + w * 32 + ql) * HDIM + s * 16 + hi * 8];

    float  lsum = 0.f;
    f32x16 oacc[2];
    #pragma unroll
    for (int dt = 0; dt < 2; ++dt)
        #pragma unroll
        for (int i = 0; i < 16; ++i) oacc[dt][i] = 0.f;

    const int nt = KEYS / 64;

    uint4 kreg[2], vreg[2];
    #define LOAD_KV(s0)                                                         \
        {                                                                       \
            _Pragma("unroll")                                                   \
            for (int ii = 0; ii < 2; ++ii) {                                    \
                const int L   = ii * 256 + tid;                                 \
                const int row = L >> 3;                                         \
                const int jl  = (L & 7) ^ (row & 7);                            \
                kreg[ii] = *(const uint4*)&Kp[(size_t)((s0) + row) * HDIM + jl * 8]; \
                vreg[ii] = *(const uint4*)&Vp[(size_t)row * TLEN + (s0) + jl * 8];   \
            }                                                                   \
        }
    #define WRITE_KV(buf)                                                       \
        {                                                                       \
            _Pragma("unroll")                                                   \
            for (int ii = 0; ii < 2; ++ii) {                                    \
                const int L = ii * 256 + tid;                                   \
                *(uint4*)&ksh[buf][L * 8] = kreg[ii];                           \
                *(uint4*)&vsh[buf][L * 8] = vreg[ii];                           \
            }                                                                   \
        }

    LOAD_KV(0)
    WRITE_KV(0)

    for (int it = 0; it < nt; ++it) {
        const int cb = it & 1;
        __syncthreads();

        if (it + 1 < nt) LOAD_KV((it + 1) * 64)   // loads land during full iter

        // ---- S^T = K Q^T : 2 key-tiles of 32, D[key=crow(reg,hi)][q=ql]
        f32x16 sacc[2];
        #pragma unroll
        for (int kt = 0; kt < 2; ++kt)
            #pragma unroll
            for (int i = 0; i < 16; ++i) sacc[kt][i] = 0.f;
        __builtin_amdgcn_s_setprio(1);
        #pragma unroll
        for (int kt = 0; kt < 2; ++kt)
            #pragma unroll
            for (int s = 0; s < 4; ++s) {
                // A = K[key=32kt+ql][d=16s+hi*8+j]; phys chunk (2s+hi)^(row&7)
                const bf16x8 kA = *(const bf16x8*)
                    &ksh[cb][(32 * kt + ql) * 64 + ((2 * s + hi) ^ ch) * 8];
                sacc[kt] = __builtin_amdgcn_mfma_f32_32x32x16_bf16(
                    kA, qB[s], sacc[kt], 0, 0, 0);
            }
        __builtin_amdgcn_s_setprio(0);

        // ---- softmax fully in-register; build PV A-frags via permlane swap
        bf16x8 paf[4];
        #pragma unroll
        for (int kt = 0; kt < 2; ++kt) {
            float p[16];
            #pragma unroll
            for (int i = 0; i < 16; ++i)
                p[i] = __builtin_amdgcn_exp2f(sacc[kt][i]);
            lsum += (((p[0] + p[1]) + (p[2] + p[3]))
                   + ((p[4] + p[5]) + (p[6] + p[7])))
                  + (((p[8] + p[9]) + (p[10] + p[11]))
                   + ((p[12] + p[13]) + (p[14] + p[15])));
            #pragma unroll
            for (int bb = 0; bb < 2; ++bb) {
                // regs 8bb..8bb+3 = keys 16bb+{0..3}(+4hi); 8bb+4..7 = +4 more
                const unsigned X0 = cvt_pk_bf16(p[8 * bb + 0], p[8 * bb + 1]);
                const unsigned X1 = cvt_pk_bf16(p[8 * bb + 2], p[8 * bb + 3]);
                const unsigned Z0 = cvt_pk_bf16(p[8 * bb + 4], p[8 * bb + 5]);
                const unsigned Z1 = cvt_pk_bf16(p[8 * bb + 6], p[8 * bb + 7]);
                // swap X's hi half with Z's lo half:
                // r[0] = [X_lo | Z_lo] (frag words 0/1), r[1] = [X_hi | Z_hi] (2/3)
                auto s02 = __builtin_amdgcn_permlane32_swap(X0, Z0, false, false);
                auto s13 = __builtin_amdgcn_permlane32_swap(X1, Z1, false, false);
                union { unsigned u[4]; bf16x8 v; } pu;
                pu.u[0] = s02[0]; pu.u[1] = s13[0];
                pu.u[2] = s02[1]; pu.u[3] = s13[1];
                paf[kt * 2 + bb] = pu.v;
            }
        }

        // ---- O += P V : A = paf (row=q=ql, k=key), B = V[key][d]
        __builtin_amdgcn_s_setprio(1);
        #pragma unroll
        for (int dt = 0; dt < 2; ++dt)
            #pragma unroll
            for (int s = 0; s < 4; ++s) {
                // B = V[key=16s+hi*8+j][d=32dt+ql]; vsh rows are d
                const bf16x8 vB = *(const bf16x8*)
                    &vsh[cb][(32 * dt + ql) * 64 + ((2 * s + hi) ^ ch) * 8];
                oacc[dt] = __builtin_amdgcn_mfma_f32_32x32x16_bf16(
                    paf[s], vB, oacc[dt], 0, 0, 0);
            }
        __builtin_amdgcn_s_setprio(0);

        if (it + 1 < nt) WRITE_KV(cb ^ 1)   // write-late: full-iter vmcnt cover
    }
    #undef LOAD_KV
    #undef WRITE_KV

    // lanes l and l^32 hold complementary key halves of the same q row
    lsum += __shfl_xor(lsum, 32);

    if (KEYS == TLEN) {
        #pragma unroll
        for (int r = 0; r < 16; ++r) {
            const int   qr   = (r & 3) + 8 * (r >> 2) + 4 * hi;
            const float inv  = 1.0f / __shfl(lsum, qr);
            const size_t orow = (size_t)b * TLEN + q0 + w * 32 + qr;
            out[orow * HDIM + ql]      = oacc[0][r] * inv;
            out[orow * HDIM + 32 + ql] = oacc[1][r] * inv;
        }
    } else {
        float* Od = (split == 0)
            ? out : O1 + (size_t)(split - 1) * NB * TLEN * HDIM;
        #pragma unroll
        for (int r = 0; r < 16; ++r) {
            const int   qr   = (r & 3) + 8 * (r >> 2) + 4 * hi;
            const size_t orow = (size_t)b * TLEN + q0 + w * 32 + qr;
            Od[orow * HDIM + ql]      = oacc[0][r];
            Od[orow * HDIM + 32 + ql] = oacc[1][r];
        }
        if (lane < 32)
            Ml[(size_t)(split * NB + b) * TLEN + q0 + w * 32 + lane] = lsum;
    }
}

// ---------------------------------------------------------------------------
// Kernel 3: merge 4 splits: out = (O0+O1+O2+O3) / (l0+l1+l2+l3)
// ---------------------------------------------------------------------------
__global__ __launch_bounds__(256) void merge_kernel(
    float* __restrict__ out, const float* __restrict__ O1,
    const float* __restrict__ Ml)
{
    const int idx  = blockIdx.x * 256 + threadIdx.x;
    const int row  = idx >> 4;
    const int col4 = (idx & 15) * 4;
    const int b    = row >> 12;
    const int t    = row & (TLEN - 1);
    float l = 0.f;
    #pragma unroll
    for (int s = 0; s < 4; ++s) l += Ml[(size_t)(s * NB + b) * TLEN + t];
    const float inv = 1.0f / l;
    float4 a = *(const float4*)&out[(size_t)row * HDIM + col4];
    #pragma unroll
    for (int s = 1; s < 4; ++s) {
        float4 p = *(const float4*)
            &O1[(size_t)(s - 1) * NB * TLEN * HDIM + (size_t)row * HDIM + col4];
        a.x += p.x; a.y += p.y; a.z += p.z; a.w += p.w;
    }
    a.x *= inv; a.y *= inv; a.z *= inv; a.w *= inv;
    *(float4*)&out[(size_t)row * HDIM + col4] = a;
}

// ---------------------------------------------------------------------------
extern "C" void kernel_launch(void* const* d_in, const int* in_sizes, int n_in,
                              void* d_out, int out_size, void* d_ws, size_t ws_size,
                              hipStream_t stream)
{
    (void)in_sizes; (void)n_in; (void)out_size;
    const float* x  = (const float*)d_in[0];
    const float* wq = (const float*)d_in[1];
    const float* wk = (const float*)d_in[2];
    const float* wv = (const float*)d_in[3];
    float* out = (float*)d_out;

    unsigned short* wbf = (unsigned short*)d_out;     // parked; consumed by qkv
    unsigned short* Qbf = (unsigned short*)d_ws;
    unsigned short* Kbf = Qbf + (size_t)NB * TLEN * HDIM;
    unsigned short* Vtb = Kbf + (size_t)NB * TLEN * HDIM;
    float* Ml = (float*)((char*)d_ws + (size_t)3 * NB * TLEN * HDIM * 2);
    float* O1 = Ml + (size_t)4 * NB * TLEN;
    const size_t ws_need = (size_t)3 * NB * TLEN * HDIM * 2     // QKV bf16
                         + (size_t)4 * NB * TLEN * 4            // Ml (4 splits)
                         + (size_t)3 * NB * TLEN * HDIM * 4;    // O1..O3
    const bool use_split = ws_size >= ws_need;

    wconv_kernel<<<dim3(192), 256, 0, stream>>>(wq, wk, wv, wbf);
    qkv_kernel<<<dim3(NB * TLEN / 32), 256, 0, stream>>>(x, wbf, Qbf, Kbf, Vtb);

    if (use_split) {
        attn_kernel<TLEN / 4><<<dim3(TLEN / 128, NB, 4), 256, 0, stream>>>(
            Qbf, Kbf, Vtb, O1, Ml, out);
        merge_kernel<<<dim3(NB * TLEN * 16 / 256), 256, 0, stream>>>(out, O1, Ml);
    } else {
        attn_kernel<TLEN><<<dim3(TLEN / 128, NB, 1), 256, 0, stream>>>(
            Qbf, Kbf, Vtb, O1, Ml, out);
    }
}

// Round 5
// 138.439 us; speedup vs baseline: 1.6025x; 1.6025x over previous
//
#include <hip/hip_runtime.h>
#include <math.h>

#define TLEN 4096
#define BD   1024
#define HDIM 64
#define NB   4

typedef __attribute__((ext_vector_type(8))) short bf16x8;
typedef __attribute__((ext_vector_type(4))) float f32x4;
typedef __attribute__((ext_vector_type(16))) float f32x16;

__device__ __forceinline__ unsigned short f2bf(float f) {
    union { float f; unsigned u; } v; v.f = f;
    unsigned r = v.u + 0x7FFF + ((v.u >> 16) & 1);   // RNE
    return (unsigned short)(r >> 16);
}

// packed f32x2 -> bf16x2 (RNE), lo = first arg. Harness-validated in R10.
__device__ __forceinline__ unsigned cvt_pk_bf16(float lo, float hi) {
    unsigned r;
    asm("v_cvt_pk_bf16_f32 %0, %1, %2" : "=v"(r) : "v"(lo), "v"(hi));
    return r;
}

// 8x fp32 -> bf16x8 via 4 packed converts
__device__ __forceinline__ bf16x8 cvt8pk(const float4 a, const float4 b) {
    union { unsigned u[4]; bf16x8 v; } r;
    r.u[0] = cvt_pk_bf16(a.x, a.y);
    r.u[1] = cvt_pk_bf16(a.z, a.w);
    r.u[2] = cvt_pk_bf16(b.x, b.y);
    r.u[3] = cvt_pk_bf16(b.z, b.w);
    return r.v;
}

// ---------------------------------------------------------------------------
// Kernel 0: weights fp32 -> bf16, wbf[192][1024]
// ---------------------------------------------------------------------------
__global__ __launch_bounds__(256) void wconv_kernel(
    const float* __restrict__ wq, const float* __restrict__ wk,
    const float* __restrict__ wv, unsigned short* __restrict__ wbf)
{
    const int r = blockIdx.x;
    const float* src = (r < 64) ? wq : (r < 128) ? wk : wv;
    const int rr = r & 63;
    const int c  = threadIdx.x * 4;
    float4 a = *(const float4*)&src[(size_t)rr * BD + c];
    uint2 o;
    o.x = cvt_pk_bf16(a.x, a.y);
    o.y = cvt_pk_bf16(a.z, a.w);
    *(uint2*)&wbf[(size_t)r * BD + c] = o;
}

// ---------------------------------------------------------------------------
// Kernel 1: QKV projection. 512 blocks x 4 waves, 32 rows/block, BK=64.
// R12 structure (1-deep reg staging, write-late; R13's 2-deep SPILLED to
// scratch: 210 MB WRITE_SIZE — reverted). R14: x staged as BF16 — fp32
// loaded to regs, cvt_pk at stage time, stored in wsh-style XOR-chunk
// layout. A-frag ds_reads 8->4 b128/iter, per-use cvt deleted (16->4
// VALU/lane/iter), xf 16->8 KB. Bit-identical numerics to R12.
// ---------------------------------------------------------------------------
__global__ __launch_bounds__(256, 2) void qkv_kernel(
    const float* __restrict__ x,
    const unsigned short* __restrict__ wbf,
    unsigned short* __restrict__ Qb,
    unsigned short* __restrict__ Kb,
    unsigned short* __restrict__ Vt)
{
    const int r0   = blockIdx.x * 32;
    const int tid  = threadIdx.x;
    const int lane = tid & 63;
    const int w    = tid >> 6;
    const int g    = lane >> 4;
    const int c    = lane & 15;

    __shared__ __align__(16) unsigned short wsh[2][192 * 64];  // 24 KB each
    __shared__ __align__(16) unsigned short xh[2][32 * 64];    // 4 KB each (bf16)
    __shared__ __align__(16) unsigned short vtr[64][40];       // V transpose

    f32x4 acc[3][2];
    #pragma unroll
    for (int t = 0; t < 3; ++t)
        #pragma unroll
        for (int rg = 0; rg < 2; ++rg) acc[t][rg] = (f32x4){0.f, 0.f, 0.f, 0.f};

    uint4 wreg[6], xreg[2];
    const int xrow = tid >> 3;              // x staging: row this thread owns
    const int xpch = tid & 7;               // phys chunk (8 bf16 = 16 B)
    const int xgch = xpch ^ (xrow & 7);     // global chunk (XOR swizzle)

    // W: coalesced loads (L2 path). lds chunk L&7 holds global (L&7)^(row&7).
    #define LOAD_W(k0s)                                                         \
        {                                                                       \
            _Pragma("unroll")                                                   \
            for (int ii = 0; ii < 6; ++ii) {                                    \
                const int L   = ii * 256 + tid;                                 \
                const int row = L >> 3;                                         \
                const int jl  = (L & 7) ^ (row & 7);                            \
                wreg[ii] = *(const uint4*)&wbf[(size_t)row * BD + (k0s) + jl * 8]; \
            }                                                                   \
        }
    #define WRITE_W(buf)                                                        \
        {                                                                       \
            _Pragma("unroll")                                                   \
            for (int ii = 0; ii < 6; ++ii) {                                    \
                const int L = ii * 256 + tid;                                   \
                *(uint4*)&wsh[buf][L * 8] = wreg[ii];                           \
            }                                                                   \
        }
    // x: coalesced fp32 loads (8 floats = 32 B per thread).
    #define LOAD_X(k0s)                                                         \
        {                                                                       \
            const float* xs = &x[(size_t)(r0 + xrow) * BD + (k0s) + xgch * 8];  \
            xreg[0] = *(const uint4*)&xs[0];                                    \
            xreg[1] = *(const uint4*)&xs[4];                                    \
        }
    // convert at stage; one ds_write_b128 per thread; layout matches wsh
    #define WRITE_X(buf)                                                        \
        {                                                                       \
            union { uint4 u; float4 f; } a0, a1;                                \
            a0.u = xreg[0]; a1.u = xreg[1];                                     \
            *(bf16x8*)&xh[buf][xrow * 64 + xpch * 8] = cvt8pk(a0.f, a1.f);      \
        }

    LOAD_W(0)
    LOAD_X(0)
    WRITE_W(0)
    WRITE_X(0)

    for (int it = 0; it < 16; ++it) {
        const int cb = it & 1;
        __syncthreads();   // buf[cb] staged (lgkm drain; vmcnt already empty)

        if (it < 15) {
            LOAD_W((it + 1) * 64)    // L2 loads into regs; latency hidden
            LOAD_X((it + 1) * 64)    //  under this iter's compute (HBM last)
        }

        #pragma unroll
        for (int h = 0; h < 2; ++h) {
            const int oct = h * 4 + g;
            const int slot = (oct ^ (c & 7)) * 8;
            bf16x8 aX[2], bW[3];
            #pragma unroll
            for (int rg = 0; rg < 2; ++rg) {
                const int row = rg * 16 + c;       // row & 7 == c & 7
                aX[rg] = *(const bf16x8*)&xh[cb][row * 64 + slot];
            }
            #pragma unroll
            for (int t = 0; t < 3; ++t)
                bW[t] = *(const bf16x8*)&wsh[cb][((w * 3 + t) * 16 + c) * 64 + slot];
            #pragma unroll
            for (int t = 0; t < 3; ++t)
                #pragma unroll
                for (int rg = 0; rg < 2; ++rg)
                    acc[t][rg] = __builtin_amdgcn_mfma_f32_16x16x32_bf16(
                        aX[rg], bW[t], acc[t][rg], 0, 0, 0);
        }

        if (it < 15) {
            WRITE_W(cb ^ 1)   // ds_write after compute; vmcnt wait covered
            WRITE_X(cb ^ 1)
        }
    }

    // ---- epilogue.  C/D frag: row = rg*16 + g*4 + i, col = c (tile m)
    const float qscale = 0.18033688f;   // 0.125 * log2(e)
    const int   bb     = r0 / TLEN;
    const int   trow   = r0 % TLEN;
    #pragma unroll
    for (int t = 0; t < 3; ++t) {
        const int m = w * 3 + t;
        #pragma unroll
        for (int rg = 0; rg < 2; ++rg)
            #pragma unroll
            for (int i = 0; i < 4; ++i) {
                const int row = rg * 16 + g * 4 + i;
                if (m < 4)
                    Qb[(size_t)(r0 + row) * HDIM + m * 16 + c]
                        = f2bf(acc[t][rg][i] * qscale);
                else if (m < 8)
                    Kb[(size_t)(r0 + row) * HDIM + (m - 4) * 16 + c]
                        = f2bf(acc[t][rg][i]);
                else
                    vtr[(m - 8) * 16 + c][row] = f2bf(acc[t][rg][i]);
            }
    }
    __syncthreads();
    {
        const int d    = tid >> 2;
        const int part = tid & 3;
        uint4 v0 = *(const uint4*)&vtr[d][part * 8];
        unsigned short* dst = Vt + (size_t)bb * HDIM * TLEN + (size_t)d * TLEN
                            + trow + part * 8;
        *(uint4*)&dst[0] = v0;
    }
    #undef LOAD_W
    #undef WRITE_W
    #undef LOAD_X
    #undef WRITE_X
}

// ---------------------------------------------------------------------------
// Kernel 2: flash attention. 256-thr blocks, 4 waves x 32 q-rows = 128q-block.
// R10: 32x32x16 MFMA path, P fully in-register (cvt_pk + permlane32_swap).
// R11: setprio(1) around MFMA clusters. (R12 version verbatim — R13's
// write-late attn variant unattributable under the qkv spill regression.)
// ---------------------------------------------------------------------------
template <int KEYS>
__global__ __launch_bounds__(256, 2) void attn_kernel(
    const unsigned short* __restrict__ Qb,
    const unsigned short* __restrict__ Kb,
    const unsigned short* __restrict__ Vt,
    float* __restrict__ O1, float* __restrict__ Ml, float* __restrict__ out)
{
    const int b     = blockIdx.y;
    const int q0    = blockIdx.x * 128;
    const int split = blockIdx.z;
    const int sbase = split * KEYS;

    const unsigned short* Qp = Qb + (size_t)b * TLEN * HDIM;
    const unsigned short* Kp = Kb + (size_t)b * TLEN * HDIM + (size_t)sbase * HDIM;
    const unsigned short* Vp = Vt + (size_t)b * HDIM * TLEN + sbase;

    const int tid  = threadIdx.x;
    const int lane = tid & 63;
    const int w    = tid >> 6;
    const int ql   = lane & 31;   // q row of S^T/O (A row, D col); d col in vB
    const int hi   = lane >> 5;
    const int ch   = lane & 7;    // XOR swizzle component

    __shared__ __align__(16) unsigned short ksh[2][4096];   // swizzled [key][d]
    __shared__ __align__(16) unsigned short vsh[2][4096];   // swizzled [d][key]

    // Q B-frags: B[k=16][col=q], col=lane&31, k=hi*8+j. qB[s] covers d=16s..16s+15
    bf16x8 qB[4];
    #pragma unroll
    for (int s = 0; s < 4; ++s)
        qB[s] = *(const bf16x8*)
            &Qp[(size_t)(q0 + w * 32 + ql) * HDIM + s * 16 + hi * 8];

    float  lsum = 0.f;
    f32x16 oacc[2];
    #pragma unroll
    for (int dt = 0; dt < 2; ++dt)
        #pragma unroll
        for (int i = 0; i < 16; ++i) oacc[dt][i] = 0.f;

    const int nt = KEYS / 64;

    uint4 kreg[2], vreg[2];
    #define LOAD_KV(s0)                                                         \
        {                                                                       \
            _Pragma("unroll")                                                   \
            for (int ii = 0; ii < 2; ++ii) {                                    \
                const int L   = ii * 256 + tid;                                 \
                const int row = L >> 3;                                         \
                const int jl  = (L & 7) ^ (row & 7);                            \
                kreg[ii] = *(const uint4*)&Kp[(size_t)((s0) + row) * HDIM + jl * 8]; \
                vreg[ii] = *(const uint4*)&Vp[(size_t)row * TLEN + (s0) + jl * 8];   \
            }                                                                   \
        }
    #define WRITE_KV(buf)                                                       \
        {                                                                       \
            _Pragma("unroll")                                                   \
            for (int ii = 0; ii < 2; ++ii) {                                    \
                const int L = ii * 256 + tid;                                   \
                *(uint4*)&ksh[buf][L * 8] = kreg[ii];                           \
                *(uint4*)&vsh[buf][L * 8] = vreg[ii];                           \
            }                                                                   \
        }

    LOAD_KV(0)
    WRITE_KV(0)

    for (int it = 0; it < nt; ++it) {
        const int cb = it & 1;
        __syncthreads();

        if (it + 1 < nt) LOAD_KV((it + 1) * 64)   // L2 loads, land during S

        // ---- S^T = K Q^T : 2 key-tiles of 32, D[key=crow(reg,hi)][q=ql]
        f32x16 sacc[2];
        #pragma unroll
        for (int kt = 0; kt < 2; ++kt)
            #pragma unroll
            for (int i = 0; i < 16; ++i) sacc[kt][i] = 0.f;
        __builtin_amdgcn_s_setprio(1);
        #pragma unroll
        for (int kt = 0; kt < 2; ++kt)
            #pragma unroll
            for (int s = 0; s < 4; ++s) {
                // A = K[key=32kt+ql][d=16s+hi*8+j]; phys chunk (2s+hi)^(row&7)
                const bf16x8 kA = *(const bf16x8*)
                    &ksh[cb][(32 * kt + ql) * 64 + ((2 * s + hi) ^ ch) * 8];
                sacc[kt] = __builtin_amdgcn_mfma_f32_32x32x16_bf16(
                    kA, qB[s], sacc[kt], 0, 0, 0);
            }
        __builtin_amdgcn_s_setprio(0);

        if (it + 1 < nt) WRITE_KV(cb ^ 1)   // dbuf: cb^1 not read this iter

        // ---- softmax fully in-register; build PV A-frags via permlane swap
        bf16x8 paf[4];
        #pragma unroll
        for (int kt = 0; kt < 2; ++kt) {
            float p[16];
            #pragma unroll
            for (int i = 0; i < 16; ++i)
                p[i] = __builtin_amdgcn_exp2f(sacc[kt][i]);
            lsum += (((p[0] + p[1]) + (p[2] + p[3]))
                   + ((p[4] + p[5]) + (p[6] + p[7])))
                  + (((p[8] + p[9]) + (p[10] + p[11]))
                   + ((p[12] + p[13]) + (p[14] + p[15])));
            #pragma unroll
            for (int bb = 0; bb < 2; ++bb) {
                // regs 8bb..8bb+3 = keys 16bb+{0..3}(+4hi); 8bb+4..7 = +4 more
                const unsigned X0 = cvt_pk_bf16(p[8 * bb + 0], p[8 * bb + 1]);
                const unsigned X1 = cvt_pk_bf16(p[8 * bb + 2], p[8 * bb + 3]);
                const unsigned Z0 = cvt_pk_bf16(p[8 * bb + 4], p[8 * bb + 5]);
                const unsigned Z1 = cvt_pk_bf16(p[8 * bb + 6], p[8 * bb + 7]);
                // swap X's hi half with Z's lo half:
                // r[0] = [X_lo | Z_lo] (frag words 0/1), r[1] = [X_hi | Z_hi] (2/3)
                auto s02 = __builtin_amdgcn_permlane32_swap(X0, Z0, false, false);
                auto s13 = __builtin_amdgcn_permlane32_swap(X1, Z1, false, false);
                union { unsigned u[4]; bf16x8 v; } pu;
                pu.u[0] = s02[0]; pu.u[1] = s13[0];
                pu.u[2] = s02[1]; pu.u[3] = s13[1];
                paf[kt * 2 + bb] = pu.v;
            }
        }

        // ---- O += P V : A = paf (row=q=ql, k=key), B = V[key][d]
        __builtin_amdgcn_s_setprio(1);
        #pragma unroll
        for (int dt = 0; dt < 2; ++dt)
            #pragma unroll
            for (int s = 0; s < 4; ++s) {
                // B = V[key=16s+hi*8+j][d=32dt+ql]; vsh rows are d
                const bf16x8 vB = *(const bf16x8*)
                    &vsh[cb][(32 * dt + ql) * 64 + ((2 * s + hi) ^ ch) * 8];
                oacc[dt] = __builtin_amdgcn_mfma_f32_32x32x16_bf16(
                    paf[s], vB, oacc[dt], 0, 0, 0);
            }
        __builtin_amdgcn_s_setprio(0);
    }
    #undef LOAD_KV
    #undef WRITE_KV

    // lanes l and l^32 hold complementary key halves of the same q row
    lsum += __shfl_xor(lsum, 32);

    if (KEYS == TLEN) {
        #pragma unroll
        for (int r = 0; r < 16; ++r) {
            const int   qr   = (r & 3) + 8 * (r >> 2) + 4 * hi;
            const float inv  = 1.0f / __shfl(lsum, qr);
            const size_t orow = (size_t)b * TLEN + q0 + w * 32 + qr;
            out[orow * HDIM + ql]      = oacc[0][r] * inv;
            out[orow * HDIM + 32 + ql] = oacc[1][r] * inv;
        }
    } else {
        float* Od = (split == 0)
            ? out : O1 + (size_t)(split - 1) * NB * TLEN * HDIM;
        #pragma unroll
        for (int r = 0; r < 16; ++r) {
            const int   qr   = (r & 3) + 8 * (r >> 2) + 4 * hi;
            const size_t orow = (size_t)b * TLEN + q0 + w * 32 + qr;
            Od[orow * HDIM + ql]      = oacc[0][r];
            Od[orow * HDIM + 32 + ql] = oacc[1][r];
        }
        if (lane < 32)
            Ml[(size_t)(split * NB + b) * TLEN + q0 + w * 32 + lane] = lsum;
    }
}

// ---------------------------------------------------------------------------
// Kernel 3: merge 4 splits: out = (O0+O1+O2+O3) / (l0+l1+l2+l3)
// ---------------------------------------------------------------------------
__global__ __launch_bounds__(256) void merge_kernel(
    float* __restrict__ out, const float* __restrict__ O1,
    const float* __restrict__ Ml)
{
    const int idx  = blockIdx.x * 256 + threadIdx.x;
    const int row  = idx >> 4;
    const int col4 = (idx & 15) * 4;
    const int b    = row >> 12;
    const int t    = row & (TLEN - 1);
    float l = 0.f;
    #pragma unroll
    for (int s = 0; s < 4; ++s) l += Ml[(size_t)(s * NB + b) * TLEN + t];
    const float inv = 1.0f / l;
    float4 a = *(const float4*)&out[(size_t)row * HDIM + col4];
    #pragma unroll
    for (int s = 1; s < 4; ++s) {
        float4 p = *(const float4*)
            &O1[(size_t)(s - 1) * NB * TLEN * HDIM + (size_t)row * HDIM + col4];
        a.x += p.x; a.y += p.y; a.z += p.z; a.w += p.w;
    }
    a.x *= inv; a.y *= inv; a.z *= inv; a.w *= inv;
    *(float4*)&out[(size_t)row * HDIM + col4] = a;
}

// ---------------------------------------------------------------------------
extern "C" void kernel_launch(void* const* d_in, const int* in_sizes, int n_in,
                              void* d_out, int out_size, void* d_ws, size_t ws_size,
                              hipStream_t stream)
{
    (void)in_sizes; (void)n_in; (void)out_size;
    const float* x  = (const float*)d_in[0];
    const float* wq = (const float*)d_in[1];
    const float* wk = (const float*)d_in[2];
    const float* wv = (const float*)d_in[3];
    float* out = (float*)d_out;

    unsigned short* wbf = (unsigned short*)d_out;     // parked; consumed by qkv
    unsigned short* Qbf = (unsigned short*)d_ws;
    unsigned short* Kbf = Qbf + (size_t)NB * TLEN * HDIM;
    unsigned short* Vtb = Kbf + (size_t)NB * TLEN * HDIM;
    float* Ml = (float*)((char*)d_ws + (size_t)3 * NB * TLEN * HDIM * 2);
    float* O1 = Ml + (size_t)4 * NB * TLEN;
    const size_t ws_need = (size_t)3 * NB * TLEN * HDIM * 2     // QKV bf16
                         + (size_t)4 * NB * TLEN * 4            // Ml (4 splits)
                         + (size_t)3 * NB * TLEN * HDIM * 4;    // O1..O3
    const bool use_split = ws_size >= ws_need;

    wconv_kernel<<<dim3(192), 256, 0, stream>>>(wq, wk, wv, wbf);
    qkv_kernel<<<dim3(NB * TLEN / 32), 256, 0, stream>>>(x, wbf, Qbf, Kbf, Vtb);

    if (use_split) {
        attn_kernel<TLEN / 4><<<dim3(TLEN / 128, NB, 4), 256, 0, stream>>>(
            Qbf, Kbf, Vtb, O1, Ml, out);
        merge_kernel<<<dim3(NB * TLEN * 16 / 256), 256, 0, stream>>>(out, O1, Ml);
    } else {
        attn_kernel<TLEN><<<dim3(TLEN / 128, NB, 1), 256, 0, stream>>>(
            Qbf, Kbf, Vtb, O1, Ml, out);
    }
}